// Round 9
// baseline (19314.075 us; speedup 1.0000x reference)
//
#include <hip/hip_runtime.h>
#include <hip/hip_bf16.h>
#include <cstdint>
#include <cstddef>

// Problem constants
#define T_LEN 1024
#define B_SZ  64
#define H_DIM 512
#define D_IN  512
#define YSLOTS 16

typedef __attribute__((ext_vector_type(8))) short short8;
typedef __attribute__((ext_vector_type(4))) float f32x4;
typedef __attribute__((ext_vector_type(4))) int   i32x4;

// LDS: Whh (one layer) 48K shared by 4 waves + 4 x 16K per-wave H/X tiles
#define OFF_WHH  0
#define OFF_TILE 49152
#define SMEM_BYTES 114688

// Tagged-unit exchange (round-6 proven format).
// Unit = 16B: u16[0..6] = 7 bf16, u16[7] = step tag (>=1; memset gives 0).
// Per state: 16 rows x (32 producers x 3 units = 1536B).
#define ROW_BYTES   1536
#define STATE_BYTES 24576
#define HT_BYTES    (32 * STATE_BYTES)           // ((layer*2+par)*2+dir)*4+bg
#define YT_BYTES    (YSLOTS * 8 * STATE_BYTES)   // ((slot*2+dir)*4+bg)

__device__ __forceinline__ int swz(int row, int byteoff) {
  return byteoff ^ ((row & 7) << 4);   // 16B-granule XOR, breaks stride-1024 conflicts
}

__device__ __forceinline__ unsigned short f2bf(float f) {
  unsigned u = __float_as_uint(f);
  return (unsigned short)((u + 0x7FFFu + ((u >> 16) & 1u)) >> 16);   // RNE
}

__device__ __forceinline__ short8 pack8(float4 a, float4 b) {
  short8 v;
  v[0] = (short)f2bf(a.x); v[1] = (short)f2bf(a.y);
  v[2] = (short)f2bf(a.z); v[3] = (short)f2bf(a.w);
  v[4] = (short)f2bf(b.x); v[5] = (short)f2bf(b.y);
  v[6] = (short)f2bf(b.z); v[7] = (short)f2bf(b.w);
  return v;
}

__device__ __forceinline__ unsigned cvtpk(float lo, float hi) {
  unsigned r;
  asm("v_cvt_pk_bf16_f32 %0, %1, %2" : "=v"(r) : "v"(lo), "v"(hi));
  return r;
}
__device__ __forceinline__ short8 cvtpk8(float4 a, float4 b) {
  union { unsigned u[4]; short8 s; } cv;
  cv.u[0] = cvtpk(a.x, a.y); cv.u[1] = cvtpk(a.z, a.w);
  cv.u[2] = cvtpk(b.x, b.y); cv.u[3] = cvtpk(b.z, b.w);
  return cv.s;
}

__device__ __forceinline__ float sigm(float x) { return 1.0f / (1.0f + __expf(-x)); }
__device__ __forceinline__ float fast_tanh(float x) { return 1.0f - 2.0f / (__expf(2.0f * x) + 1.0f); }

__device__ __forceinline__ void st16(void* p, i32x4 d) {
  asm volatile("global_store_dwordx4 %0, %1, off sc1" :: "v"(p), "v"(d) : "memory");
}

// two producers' 7/7/2-packed triples -> contiguous bf16x8 pairs (round-6 proven)
__device__ __forceinline__ void repack_triple(i32x4 Ua, i32x4 Ub, i32x4 Uc,
                                              short8& s0, short8& s1) {
  union { unsigned u[4]; short8 s; } A, B;
  A.u[0] = (unsigned)Ua[0];
  A.u[1] = (unsigned)Ua[1];
  A.u[2] = (unsigned)Ua[2];
  A.u[3] = ((unsigned)Ua[3] & 0xffffu) | ((unsigned)Ub[0] << 16);
  B.u[0] = ((unsigned)Ub[0] >> 16) | ((unsigned)Ub[1] << 16);
  B.u[1] = ((unsigned)Ub[1] >> 16) | ((unsigned)Ub[2] << 16);
  B.u[2] = ((unsigned)Ub[2] >> 16) | (((unsigned)Ub[3] & 0xffffu) << 16);
  B.u[3] = (unsigned)Uc[0];
  s0 = A.s; s1 = B.s;
}

__global__ __launch_bounds__(256, 1)
void gru_wave(const float* __restrict__ x,
              const float* __restrict__ enc,
              const float* __restrict__ WihF, const float* __restrict__ WhhF,
              const float* __restrict__ bihF, const float* __restrict__ bhhF,
              const float* __restrict__ WihB, const float* __restrict__ WhhB,
              const float* __restrict__ bihB, const float* __restrict__ bhhB,
              float* __restrict__ dout,
              char* __restrict__ hT,
              char* __restrict__ yT)
{
  __shared__ alignas(16) char smem[SMEM_BYTES];

  const int bid   = blockIdx.x;
  const int layer = bid >> 6;          // 0..1
  const int dirr  = (bid >> 5) & 1;    // 0..1
  const int cg    = bid & 31;          // col-group (16 cols)
  const int tid   = threadIdx.x;
  const int bg    = tid >> 6;          // wave = batch group
  const int lane  = tid & 63;
  const int frow  = lane & 15;         // fragment row (batch row / weight col / gather row)
  const int q     = lane >> 4;         // k-quarter / row-quarter
  const int hc0   = cg * 16;
  const int hcol  = hc0 + frow;
  const bool isPub = (frow == 0) | (frow == 7) | (frow == 14);
  const int  which = (frow == 0) ? 0 : ((frow == 7) ? 1 : 2);

  const float* Wih = ((dirr ? WihB : WihF)) + (size_t)layer * 3 * H_DIM * D_IN;
  const float* Whh = ((dirr ? WhhB : WhhF)) + (size_t)layer * 3 * H_DIM * H_DIM;
  const float* bih = ((dirr ? bihB : bihF)) + (size_t)layer * 3 * H_DIM;
  const float* bhh = ((dirr ? bhhB : bhhF)) + (size_t)layer * 3 * H_DIM;

  // ---- Stage Whh (one layer) into LDS, block-cooperative ----
  {
    const int tb = tid >> 4, tcc = tid & 15;
    #pragma unroll
    for (int g = 0; g < 3; ++g) {
      const float* s = Whh + (size_t)(g * H_DIM + hc0 + tb) * H_DIM + tcc * 32;
      char* r = smem + OFF_WHH + g * 16384 + tb * 1024;
      #pragma unroll
      for (int u = 0; u < 4; ++u) {
        float4 a = ((const float4*)s)[u * 2];
        float4 b = ((const float4*)s)[u * 2 + 1];
        *(short8*)(r + swz(tb, tcc * 64 + u * 16)) = pack8(a, b);
      }
    }
  }

  // ---- Wih B-fragments in registers (all 3 gates, 48 x 16B) ----
  short8 wf[48];
  #pragma unroll
  for (int g = 0; g < 3; ++g) {
    #pragma unroll
    for (int kc = 0; kc < 16; ++kc) {
      const float* p = Wih + (size_t)(g * H_DIM + hc0 + frow) * D_IN + kc * 32 + q * 8;
      wf[g * 16 + kc] = cvtpk8(*(const float4*)p, *(const float4*)(p + 4));
    }
  }

  // ---- biases (per lane: gate col = hcol) and h fragment init ----
  const float b_r  = bih[hcol] + bhh[hcol];
  const float b_z  = bih[H_DIM + hcol] + bhh[H_DIM + hcol];
  const float b_xn = bih[2 * H_DIM + hcol];
  const float b_hn = bhh[2 * H_DIM + hcol];
  float h[4];
  #pragma unroll
  for (int i = 0; i < 4; ++i) {
    const int brow = bg * 16 + q * 4 + i;
    h[i] = enc[(size_t)layer * B_SZ * 2 * H_DIM + (size_t)brow * 2 * H_DIM + dirr * H_DIM + hcol];
  }

  const int tileOff = OFF_TILE + bg * 16384;

  auto stateH = [&](int par) -> char* {
    return hT + (size_t)((((layer * 2 + par) * 2) + dirr) * 4 + bg) * STATE_BYTES;
  };
  auto stateY = [&](int slot) -> char* {
    return yT + (size_t)((slot * 2 + dirr) * 4 + bg) * STATE_BYTES;
  };

  // ---- publish: 4 rounds (rows q*4+i), shfl 7-pack, tagged 16B sc1 stores ----
  auto pubRounds = [&](const float* hv, char* b1, unsigned tag1, char* b2, unsigned tag2) {
    #pragma unroll
    for (int i = 0; i < 4; ++i) {
      unsigned v  = f2bf(hv[i]);
      unsigned v1 = __shfl_down(v, 1), v2 = __shfl_down(v, 2), v3 = __shfl_down(v, 3);
      unsigned v4 = __shfl_down(v, 4), v5 = __shfl_down(v, 5), v6 = __shfl_down(v, 6);
      if (isPub) {
        i32x4 U;
        U[0] = (int)(v  | (v1 << 16));
        U[1] = (int)(v2 | (v3 << 16));
        U[2] = (int)(v4 | (v5 << 16));
        U[3] = (int)((v6 & 0xffffu) | (tag1 << 16));
        const size_t off = (size_t)(q * 4 + i) * ROW_BYTES + cg * 48 + which * 16;
        st16(b1 + off, U);
        if (b2) {
          U[3] = (int)((v6 & 0xffffu) | (tag2 << 16));
          st16(b2 + off, U);
        }
      }
    }
  };

  // ---- wave gather: 24 tagged units (4 producer-pairs x 6), one wait, __all ----
  auto issue6 = [&](const char* a, i32x4& u0, i32x4& u1, i32x4& u2,
                    i32x4& u3, i32x4& u4, i32x4& u5) {
    asm volatile(
      "global_load_dwordx4 %0, %6, off sc1\n\t"
      "global_load_dwordx4 %1, %6, off offset:16 sc1\n\t"
      "global_load_dwordx4 %2, %6, off offset:32 sc1\n\t"
      "global_load_dwordx4 %3, %6, off offset:48 sc1\n\t"
      "global_load_dwordx4 %4, %6, off offset:64 sc1\n\t"
      "global_load_dwordx4 %5, %6, off offset:80 sc1"
      : "=&v"(u0), "=&v"(u1), "=&v"(u2), "=&v"(u3), "=&v"(u4), "=&v"(u5)
      : "v"(a) : "memory");
  };
  auto issue24 = [&](const char* base, i32x4* U) {
    const char* a = base + (size_t)frow * ROW_BYTES + q * 96;   // pair p=q+4j at +384j
    issue6(a,        U[0],  U[1],  U[2],  U[3],  U[4],  U[5]);
    issue6(a + 384,  U[6],  U[7],  U[8],  U[9],  U[10], U[11]);
    issue6(a + 768,  U[12], U[13], U[14], U[15], U[16], U[17]);
    issue6(a + 1152, U[18], U[19], U[20], U[21], U[22], U[23]);
  };
  auto gatherRetry = [&](const char* base, unsigned tag, i32x4* U) {
    for (;;) {
      asm volatile("s_waitcnt vmcnt(0)" ::: "memory");
      __builtin_amdgcn_sched_barrier(0);
      bool ok = true;
      #pragma unroll
      for (int j = 0; j < 24; ++j) ok &= ((((unsigned)U[j][3]) >> 16) == tag);
      if (__all(ok)) break;
      __builtin_amdgcn_s_sleep(1);
      issue24(base, U);
    }
  };
  auto repackAll = [&](const i32x4* U, int tOff) {
    char* lrow = smem + tOff + frow * 1024;
    #pragma unroll
    for (int j = 0; j < 4; ++j) {
      const int p = q + 4 * j;
      short8 s0, s1, s2, s3;
      repack_triple(U[6 * j],     U[6 * j + 1], U[6 * j + 2], s0, s1);
      repack_triple(U[6 * j + 3], U[6 * j + 4], U[6 * j + 5], s2, s3);
      *(short8*)(lrow + swz(frow, 64 * p))      = s0;
      *(short8*)(lrow + swz(frow, 64 * p + 16)) = s1;
      *(short8*)(lrow + swz(frow, 64 * p + 32)) = s2;
      *(short8*)(lrow + swz(frow, 64 * p + 48)) = s3;
    }
  };

  // ---- per-wave x staging (fp32 global -> bf16 tile) ----
  auto stage_x = [&](int pos) {
    const float* src = x + ((size_t)(bg * 16 + frow) * T_LEN + pos) * D_IN + q * 128;
    char* lrow = smem + tileOff + frow * 1024;
    #pragma unroll
    for (int u = 0; u < 16; ++u) {
      float4 a = ((const float4*)src)[u * 2];
      float4 b = ((const float4*)src)[u * 2 + 1];
      *(short8*)(lrow + swz(frow, q * 256 + u * 16)) = pack8(a, b);
    }
  };

  // ---- MFMA phases (single wave, all 3 gates) ----
  auto xpart = [&](f32x4& ar, f32x4& az, f32x4& axn) {
    char* tr = smem + tileOff + frow * 1024;
    #pragma unroll
    for (int kc = 0; kc < 16; ++kc) {
      short8 a = *(const short8*)(tr + swz(frow, kc * 64 + q * 16));
      ar  = __builtin_amdgcn_mfma_f32_16x16x32_bf16(a, wf[kc],      ar,  0, 0, 0);
      az  = __builtin_amdgcn_mfma_f32_16x16x32_bf16(a, wf[16 + kc], az,  0, 0, 0);
      axn = __builtin_amdgcn_mfma_f32_16x16x32_bf16(a, wf[32 + kc], axn, 0, 0, 0);
    }
  };
  auto hpart = [&](f32x4& ar, f32x4& az, f32x4& ahn) {
    char* tr = smem + tileOff + frow * 1024;
    char* w0 = smem + OFF_WHH + frow * 1024;
    #pragma unroll
    for (int kc = 0; kc < 16; ++kc) {
      const int o = swz(frow, kc * 64 + q * 16);
      short8 a  = *(const short8*)(tr + o);
      short8 br = *(const short8*)(w0 + o);
      short8 bz = *(const short8*)(w0 + 16384 + o);
      short8 bn = *(const short8*)(w0 + 32768 + o);
      ar  = __builtin_amdgcn_mfma_f32_16x16x32_bf16(a, br, ar,  0, 0, 0);
      az  = __builtin_amdgcn_mfma_f32_16x16x32_bf16(a, bz, az,  0, 0, 0);
      ahn = __builtin_amdgcn_mfma_f32_16x16x32_bf16(a, bn, ahn, 0, 0, 0);
    }
  };

  // ---- init publish h(0) (tag 1, parity 0) ----
  pubRounds(h, stateH(0), 1u, nullptr, 0u);
  __syncthreads();   // Whh staged (only barrier in the kernel)

  i32x4 U[24];
  f32x4 curR = {0.f,0.f,0.f,0.f}, curZ = {0.f,0.f,0.f,0.f}, curXN = {0.f,0.f,0.f,0.f};

  // ---- prologue: x-part for step 0 ----
  if (layer == 0) {
    stage_x(dirr ? (T_LEN - 1) : 0);
    xpart(curR, curZ, curXN);
  } else {
    issue24(stateY(0), U);
    gatherRetry(stateY(0), 1u, U);
    repackAll(U, tileOff);
    xpart(curR, curZ, curXN);
  }

  for (int t = 0; t < T_LEN; ++t) {
    // ---- L0 backpressure: don't overwrite y slot t&15 until L1 consumed it ----
    if (layer == 0 && t >= YSLOTS) {
      const char* bp = hT + (size_t)(((2 + ((t + 1) & 1)) * 2 + dirr) * 4 + bg) * STATE_BYTES
                     + cg * 48;
      for (;;) {
        i32x4 Ub;
        asm volatile("global_load_dwordx4 %0, %1, off sc1\n\ts_waitcnt vmcnt(0)"
                     : "=&v"(Ub) : "v"(bp) : "memory");
        __builtin_amdgcn_sched_barrier(0);
        if (((unsigned)Ub[3] >> 16) >= (unsigned)(t - (YSLOTS - 2))) break;
        __builtin_amdgcn_s_sleep(1);
      }
    }

    // ---- issue h(t) gather; L0 hides the RT under stage_x+xpart(t+1) ----
    char* hs = stateH(t & 1);
    issue24(hs, U);
    f32x4 nR = {0.f,0.f,0.f,0.f}, nZ = {0.f,0.f,0.f,0.f}, nXN = {0.f,0.f,0.f,0.f};
    if (layer == 0 && t + 1 < T_LEN) {
      stage_x(dirr ? (T_LEN - 2 - t) : (t + 1));   // tile free (h(t-1) consumed)
      xpart(nR, nZ, nXN);
    }
    gatherRetry(hs, (unsigned)(t + 1), U);
    repackAll(U, tileOff);                          // tile := h(t)

    // ---- L1: issue y(t+1) early; its RT hides under hpart+gates+publish ----
    if (layer == 1 && t + 1 < T_LEN) issue24(stateY((t + 1) & (YSLOTS - 1)), U);

    // ---- h-part MFMAs + in-register gates ----
    f32x4 aHN = {0.f,0.f,0.f,0.f};
    hpart(curR, curZ, aHN);
    #pragma unroll
    for (int i = 0; i < 4; ++i) {
      const float r = sigm(curR[i] + b_r);
      const float z = sigm(curZ[i] + b_z);
      const float n = fast_tanh(curXN[i] + b_xn + r * (aHN[i] + b_hn));
      h[i] = (1.0f - z) * n + z * h[i];
    }

    // ---- publish h(t+1) (+ y0(t) for L0); L1 writes y1 to dout ----
    if (layer == 0) {
      pubRounds(h, stateH((t + 1) & 1), (unsigned)(t + 2),
                stateY(t & (YSLOTS - 1)), (unsigned)(t + 1));
    } else {
      pubRounds(h, stateH((t + 1) & 1), (unsigned)(t + 2), nullptr, 0u);
      const int torig = dirr ? (T_LEN - 1 - t) : t;
      #pragma unroll
      for (int i = 0; i < 4; ++i) {
        const int brow = bg * 16 + q * 4 + i;
        dout[(size_t)brow * T_LEN * 2 * H_DIM + (size_t)torig * 2 * H_DIM + dirr * H_DIM + hcol] = h[i];
      }
    }
    if (t == T_LEN - 1) {
      #pragma unroll
      for (int i = 0; i < 4; ++i) {
        const int brow = bg * 16 + q * 4 + i;
        dout[(size_t)B_SZ * T_LEN * 2 * H_DIM +
             (size_t)(layer * B_SZ + brow) * 2 * H_DIM + dirr * H_DIM + hcol] = h[i];
      }
    }

    // ---- tails: next step's x-part ----
    if (layer == 0) {
      curR = nR; curZ = nZ; curXN = nXN;
    } else if (t + 1 < T_LEN) {
      gatherRetry(stateY((t + 1) & (YSLOTS - 1)), (unsigned)(t + 2), U);
      repackAll(U, tileOff);                        // tile := y0(t+1)
      curR[0]=curR[1]=curR[2]=curR[3]=0.f;
      curZ[0]=curZ[1]=curZ[2]=curZ[3]=0.f;
      curXN[0]=curXN[1]=curXN[2]=curXN[3]=0.f;
      xpart(curR, curZ, curXN);
    }
  }
}

extern "C" void kernel_launch(void* const* d_in, const int* in_sizes, int n_in,
                              void* d_out, int out_size, void* d_ws, size_t ws_size,
                              hipStream_t stream) {
  (void)in_sizes; (void)n_in; (void)out_size; (void)ws_size;
  const float* x    = (const float*)d_in[0];
  const float* enc  = (const float*)d_in[1];
  const float* WihF = (const float*)d_in[2];
  const float* WhhF = (const float*)d_in[3];
  const float* bihF = (const float*)d_in[4];
  const float* bhhF = (const float*)d_in[5];
  const float* WihB = (const float*)d_in[6];
  const float* WhhB = (const float*)d_in[7];
  const float* bihB = (const float*)d_in[8];
  const float* bhhB = (const float*)d_in[9];
  float* out = (float*)d_out;

  char* hT = (char*)d_ws;                 // 768KB tagged h exchange
  char* yT = (char*)d_ws + HT_BYTES;      // 3MB tagged y0 ring (16 slots)
  // zero ALL tags each replay (tags count from 1; memset-0 never matches)
  hipMemsetAsync(d_ws, 0, HT_BYTES + YT_BYTES, stream);

  dim3 grid(128), block(256);
  gru_wave<<<grid, block, 0, stream>>>(x, enc, WihF, WhhF, bihF, bhhF,
                                       WihB, WhhB, bihB, bhhB, out, hT, yT);
}

// Round 10
// 13565.294 us; speedup vs baseline: 1.4238x; 1.4238x over previous
//
#include <hip/hip_runtime.h>
#include <hip/hip_bf16.h>
#include <cstdint>
#include <cstddef>

// Problem constants
#define T_LEN 1024
#define B_SZ  64
#define H_DIM 512
#define D_IN  512
#define YSLOTS 16

typedef __attribute__((ext_vector_type(8))) short short8;
typedef __attribute__((ext_vector_type(4))) float f32x4;
typedef __attribute__((ext_vector_type(4))) int   i32x4;

// Decomposition: 256 blocks x 128 threads. block = (layer, dir, bg, cg16).
// wave s in {0,1} = rows [bg*32+s*16, +16), cols [cg*16, +16): an autonomous chain.
// LDS: Whh 48K | Wih 48K | 2 x 16K per-wave tile = 128K -> 1 block/CU
#define OFF_WHH  0
#define OFF_WIH  49152
#define OFF_TILE 98304
#define SMEM_BYTES 131072

// Tagged-unit exchange (round-6 proven format).
// Unit = 16B: u16[0..6] = 7 bf16, u16[7] = step tag (>=1; memset gives 0).
// Per state: 16 rows x (32 producers x 3 units = 1536B).
#define ROW_BYTES   1536
#define STATE_BYTES 24576
#define HT_BYTES    (32 * STATE_BYTES)            // ((((L*2+par)*2+D)*2+bg)*2+s)
#define YT_BYTES    (YSLOTS * 8 * STATE_BYTES)    // ((((slot*2+D)*2+bg)*2+s)

__device__ __forceinline__ int swz(int row, int byteoff) {
  return byteoff ^ ((row & 7) << 4);   // 16B-granule XOR, breaks stride-1024 conflicts
}

__device__ __forceinline__ unsigned short f2bf(float f) {
  unsigned u = __float_as_uint(f);
  return (unsigned short)((u + 0x7FFFu + ((u >> 16) & 1u)) >> 16);   // RNE
}

__device__ __forceinline__ short8 pack8(float4 a, float4 b) {
  short8 v;
  v[0] = (short)f2bf(a.x); v[1] = (short)f2bf(a.y);
  v[2] = (short)f2bf(a.z); v[3] = (short)f2bf(a.w);
  v[4] = (short)f2bf(b.x); v[5] = (short)f2bf(b.y);
  v[6] = (short)f2bf(b.z); v[7] = (short)f2bf(b.w);
  return v;
}

__device__ __forceinline__ float sigm(float x) { return 1.0f / (1.0f + __expf(-x)); }
__device__ __forceinline__ float fast_tanh(float x) { return 1.0f - 2.0f / (__expf(2.0f * x) + 1.0f); }

__device__ __forceinline__ void st16(void* p, i32x4 d) {
  asm volatile("global_store_dwordx4 %0, %1, off sc1" :: "v"(p), "v"(d) : "memory");
}

// two producers' 7/7/2-packed triples -> contiguous bf16x8 pairs (round-6 proven)
__device__ __forceinline__ void repack_triple(i32x4 Ua, i32x4 Ub, i32x4 Uc,
                                              short8& s0, short8& s1) {
  union { unsigned u[4]; short8 s; } A, B;
  A.u[0] = (unsigned)Ua[0];
  A.u[1] = (unsigned)Ua[1];
  A.u[2] = (unsigned)Ua[2];
  A.u[3] = ((unsigned)Ua[3] & 0xffffu) | ((unsigned)Ub[0] << 16);
  B.u[0] = ((unsigned)Ub[0] >> 16) | ((unsigned)Ub[1] << 16);
  B.u[1] = ((unsigned)Ub[1] >> 16) | ((unsigned)Ub[2] << 16);
  B.u[2] = ((unsigned)Ub[2] >> 16) | (((unsigned)Ub[3] & 0xffffu) << 16);
  B.u[3] = (unsigned)Uc[0];
  s0 = A.s; s1 = B.s;
}

__global__ __launch_bounds__(128, 1)
void gru_wave2(const float* __restrict__ x,
               const float* __restrict__ enc,
               const float* __restrict__ WihF, const float* __restrict__ WhhF,
               const float* __restrict__ bihF, const float* __restrict__ bhhF,
               const float* __restrict__ WihB, const float* __restrict__ WhhB,
               const float* __restrict__ bihB, const float* __restrict__ bhhB,
               float* __restrict__ dout,
               char* __restrict__ hT,
               char* __restrict__ yT)
{
  __shared__ alignas(16) char smem[SMEM_BYTES];

  const int bid   = blockIdx.x;
  const int layer = bid >> 7;
  const int dirr  = (bid >> 6) & 1;
  const int bg    = (bid >> 5) & 1;
  const int cg    = bid & 31;
  const int tid   = threadIdx.x;
  const int s     = tid >> 6;          // wave id (row half)
  const int lane  = tid & 63;
  const int frow  = lane & 15;
  const int q     = lane >> 4;
  const int hc0   = cg * 16;
  const int hcol  = hc0 + frow;
  const int rowbase = bg * 32 + s * 16;
  const bool isPub = (frow == 0) | (frow == 7) | (frow == 14);
  const int  which = (frow == 0) ? 0 : ((frow == 7) ? 1 : 2);

  const float* Wih = ((dirr ? WihB : WihF)) + (size_t)layer * 3 * H_DIM * D_IN;
  const float* Whh = ((dirr ? WhhB : WhhF)) + (size_t)layer * 3 * H_DIM * H_DIM;
  const float* bih = ((dirr ? bihB : bihF)) + (size_t)layer * 3 * H_DIM;
  const float* bhh = ((dirr ? bhhB : bhhF)) + (size_t)layer * 3 * H_DIM;

  // ---- Stage Whh AND Wih into LDS (block-cooperative, once) ----
  {
    const int tb = tid >> 3, tcc = tid & 7;     // 16 rows x 8 col-segments (64 cols)
    #pragma unroll
    for (int g = 0; g < 3; ++g) {
      const float* sH = Whh + (size_t)(g * H_DIM + hc0 + tb) * H_DIM + tcc * 64;
      const float* sI = Wih + (size_t)(g * H_DIM + hc0 + tb) * D_IN + tcc * 64;
      char* rH = smem + OFF_WHH + g * 16384 + tb * 1024;
      char* rI = smem + OFF_WIH + g * 16384 + tb * 1024;
      #pragma unroll
      for (int u = 0; u < 8; ++u) {
        float4 a = ((const float4*)sH)[u * 2];
        float4 b = ((const float4*)sH)[u * 2 + 1];
        *(short8*)(rH + swz(tb, tcc * 128 + u * 16)) = pack8(a, b);
        float4 c = ((const float4*)sI)[u * 2];
        float4 d = ((const float4*)sI)[u * 2 + 1];
        *(short8*)(rI + swz(tb, tcc * 128 + u * 16)) = pack8(c, d);
      }
    }
  }

  // ---- biases (gate col = hcol) and h fragment init ----
  const float b_r  = bih[hcol] + bhh[hcol];
  const float b_z  = bih[H_DIM + hcol] + bhh[H_DIM + hcol];
  const float b_xn = bih[2 * H_DIM + hcol];
  const float b_hn = bhh[2 * H_DIM + hcol];
  float h[4];
  #pragma unroll
  for (int i = 0; i < 4; ++i) {
    const int brow = rowbase + q * 4 + i;
    h[i] = enc[(size_t)layer * B_SZ * 2 * H_DIM + (size_t)brow * 2 * H_DIM + dirr * H_DIM + hcol];
  }

  const int tileOff = OFF_TILE + s * 16384;

  auto stateH = [&](int par) -> char* {
    return hT + (size_t)(((((layer * 2 + par) * 2 + dirr) * 2 + bg) * 2) + s) * STATE_BYTES;
  };
  auto stateY = [&](int slot) -> char* {
    return yT + (size_t)(((((slot * 2) + dirr) * 2 + bg) * 2) + s) * STATE_BYTES;
  };

  // ---- publish: 4 rounds (rows q*4+i), shfl 7-pack, tagged 16B sc1 stores ----
  auto pubRounds = [&](const float* hv, char* b1, unsigned tag1, char* b2, unsigned tag2) {
    #pragma unroll
    for (int i = 0; i < 4; ++i) {
      unsigned v  = f2bf(hv[i]);
      unsigned v1 = __shfl_down(v, 1), v2 = __shfl_down(v, 2), v3 = __shfl_down(v, 3);
      unsigned v4 = __shfl_down(v, 4), v5 = __shfl_down(v, 5), v6 = __shfl_down(v, 6);
      if (isPub) {
        i32x4 U;
        U[0] = (int)(v  | (v1 << 16));
        U[1] = (int)(v2 | (v3 << 16));
        U[2] = (int)(v4 | (v5 << 16));
        U[3] = (int)((v6 & 0xffffu) | (tag1 << 16));
        const size_t off = (size_t)(q * 4 + i) * ROW_BYTES + cg * 48 + which * 16;
        st16(b1 + off, U);
        if (b2) {
          U[3] = (int)((v6 & 0xffffu) | (tag2 << 16));
          st16(b2 + off, U);
        }
      }
    }
  };

  // ---- gather: 24 tagged units/lane; predicated retry + backoff (anti-flood) ----
  auto issue6 = [&](const char* a, i32x4& u0, i32x4& u1, i32x4& u2,
                    i32x4& u3, i32x4& u4, i32x4& u5) {
    asm volatile(
      "global_load_dwordx4 %0, %6, off sc1\n\t"
      "global_load_dwordx4 %1, %6, off offset:16 sc1\n\t"
      "global_load_dwordx4 %2, %6, off offset:32 sc1\n\t"
      "global_load_dwordx4 %3, %6, off offset:48 sc1\n\t"
      "global_load_dwordx4 %4, %6, off offset:64 sc1\n\t"
      "global_load_dwordx4 %5, %6, off offset:80 sc1"
      : "=&v"(u0), "=&v"(u1), "=&v"(u2), "=&v"(u3), "=&v"(u4), "=&v"(u5)
      : "v"(a) : "memory");
  };
  auto issue24 = [&](const char* base, i32x4* U) {
    const char* a = base + (size_t)frow * ROW_BYTES + q * 96;   // pair p=q+4j at +384j
    issue6(a,        U[0],  U[1],  U[2],  U[3],  U[4],  U[5]);
    issue6(a + 384,  U[6],  U[7],  U[8],  U[9],  U[10], U[11]);
    issue6(a + 768,  U[12], U[13], U[14], U[15], U[16], U[17]);
    issue6(a + 1152, U[18], U[19], U[20], U[21], U[22], U[23]);
  };
  auto check24 = [&](const i32x4* U, unsigned tag) -> bool {
    bool ok = true;
    #pragma unroll
    for (int j = 0; j < 24; ++j) ok &= ((((unsigned)U[j][3]) >> 16) == tag);
    return ok;
  };
  auto gatherRetry = [&](const char* base, unsigned tag, i32x4* U) {
    asm volatile("s_waitcnt vmcnt(0)" ::: "memory");
    __builtin_amdgcn_sched_barrier(0);
    bool ok = check24(U, tag);
    while (!__all(ok)) {
      __builtin_amdgcn_s_sleep(8);          // ~0.2us backoff (anti-flood)
      if (!ok) issue24(base, U);            // per-lane predicated re-issue
      asm volatile("s_waitcnt vmcnt(0)" ::: "memory");
      __builtin_amdgcn_sched_barrier(0);
      if (!ok) ok = check24(U, tag);
    }
  };
  auto repackAll = [&](const i32x4* U) {
    char* lrow = smem + tileOff + frow * 1024;
    #pragma unroll
    for (int j = 0; j < 4; ++j) {
      const int p = q + 4 * j;
      short8 s0, s1, s2, s3;
      repack_triple(U[6 * j],     U[6 * j + 1], U[6 * j + 2], s0, s1);
      repack_triple(U[6 * j + 3], U[6 * j + 4], U[6 * j + 5], s2, s3);
      *(short8*)(lrow + swz(frow, 64 * p))      = s0;
      *(short8*)(lrow + swz(frow, 64 * p + 16)) = s1;
      *(short8*)(lrow + swz(frow, 64 * p + 32)) = s2;
      *(short8*)(lrow + swz(frow, 64 * p + 48)) = s3;
    }
  };

  // ---- per-wave x staging (fp32 global -> bf16 tile) ----
  auto stage_x = [&](int pos) {
    const float* src = x + ((size_t)(rowbase + frow) * T_LEN + pos) * D_IN + q * 128;
    char* lrow = smem + tileOff + frow * 1024;
    #pragma unroll
    for (int u = 0; u < 16; ++u) {
      float4 a = ((const float4*)src)[u * 2];
      float4 b = ((const float4*)src)[u * 2 + 1];
      *(short8*)(lrow + swz(frow, q * 256 + u * 16)) = pack8(a, b);
    }
  };

  // ---- MFMA phases (single wave, all 3 gates; B-operands from LDS) ----
  auto xpart = [&](f32x4& ar, f32x4& az, f32x4& axn) {
    char* tr = smem + tileOff + frow * 1024;
    char* w0 = smem + OFF_WIH + frow * 1024;
    #pragma unroll
    for (int kc = 0; kc < 16; ++kc) {
      const int o = swz(frow, kc * 64 + q * 16);
      short8 a  = *(const short8*)(tr + o);
      short8 br = *(const short8*)(w0 + o);
      short8 bz = *(const short8*)(w0 + 16384 + o);
      short8 bn = *(const short8*)(w0 + 32768 + o);
      ar  = __builtin_amdgcn_mfma_f32_16x16x32_bf16(a, br, ar,  0, 0, 0);
      az  = __builtin_amdgcn_mfma_f32_16x16x32_bf16(a, bz, az,  0, 0, 0);
      axn = __builtin_amdgcn_mfma_f32_16x16x32_bf16(a, bn, axn, 0, 0, 0);
    }
  };
  auto hpart = [&](f32x4& ar, f32x4& az, f32x4& ahn) {
    char* tr = smem + tileOff + frow * 1024;
    char* w0 = smem + OFF_WHH + frow * 1024;
    #pragma unroll
    for (int kc = 0; kc < 16; ++kc) {
      const int o = swz(frow, kc * 64 + q * 16);
      short8 a  = *(const short8*)(tr + o);
      short8 br = *(const short8*)(w0 + o);
      short8 bz = *(const short8*)(w0 + 16384 + o);
      short8 bn = *(const short8*)(w0 + 32768 + o);
      ar  = __builtin_amdgcn_mfma_f32_16x16x32_bf16(a, br, ar,  0, 0, 0);
      az  = __builtin_amdgcn_mfma_f32_16x16x32_bf16(a, bz, az,  0, 0, 0);
      ahn = __builtin_amdgcn_mfma_f32_16x16x32_bf16(a, bn, ahn, 0, 0, 0);
    }
  };

  // ---- init publish h(0) (tag 1, parity 0); then weights barrier ----
  pubRounds(h, stateH(0), 1u, nullptr, 0u);
  __syncthreads();   // weights staged (only barrier in the kernel)

  i32x4 U[24];
  f32x4 curR = {0.f,0.f,0.f,0.f}, curZ = {0.f,0.f,0.f,0.f}, curXN = {0.f,0.f,0.f,0.f};

  // ---- prologue: x-part for step 0 ----
  if (layer == 0) {
    stage_x(dirr ? (T_LEN - 1) : 0);
    xpart(curR, curZ, curXN);
  } else {
    issue24(stateY(0), U);
    gatherRetry(stateY(0), 1u, U);
    repackAll(U);
    xpart(curR, curZ, curXN);
  }

  for (int t = 0; t < T_LEN; ++t) {
    // ---- L0 backpressure, amortized: every 8 steps, require ALL 32 L1 waves
    //      of this community past step t-6 (tag >= t-4). Margin proof: the next
    //      8 steps overwrite ring entries <= y(t-9); L1 has gathered y(t-5). ----
    if (layer == 0 && t >= 16 && (t & 7) == 0) {
      const char* b0 = hT + (size_t)((((2 /*L1,par0*/) * 2 + dirr) * 2 + bg) * 2 + s) * STATE_BYTES
                     + (lane & 31) * 48;
      const char* b1 = hT + (size_t)((((3 /*L1,par1*/) * 2 + dirr) * 2 + bg) * 2 + s) * STATE_BYTES
                     + (lane & 31) * 48;
      for (;;) {
        i32x4 Ua, Ub;
        asm volatile(
          "global_load_dwordx4 %0, %2, off sc1\n\t"
          "global_load_dwordx4 %1, %3, off sc1\n\t"
          "s_waitcnt vmcnt(0)"
          : "=&v"(Ua), "=&v"(Ub) : "v"(b0), "v"(b1) : "memory");
        __builtin_amdgcn_sched_barrier(0);
        const unsigned m0 = (unsigned)Ua[3] >> 16, m1 = (unsigned)Ub[3] >> 16;
        const unsigned m = m0 > m1 ? m0 : m1;
        if (__all(m >= (unsigned)(t - 4))) break;
        __builtin_amdgcn_s_sleep(16);
      }
    }

    // ---- issue h(t) gather; L0 hides transit under stage_x+xpart(t+1) ----
    char* hs = stateH(t & 1);
    issue24(hs, U);
    f32x4 nR = {0.f,0.f,0.f,0.f}, nZ = {0.f,0.f,0.f,0.f}, nXN = {0.f,0.f,0.f,0.f};
    if (layer == 0 && t + 1 < T_LEN) {
      stage_x(dirr ? (T_LEN - 2 - t) : (t + 1));   // tile free (h(t-1) consumed)
      xpart(nR, nZ, nXN);
    }
    gatherRetry(hs, (unsigned)(t + 1), U);
    repackAll(U);                                   // tile := h(t)

    // ---- L1: issue y(t+1) early; transit hides under hpart+gates+publish ----
    if (layer == 1 && t + 1 < T_LEN) issue24(stateY((t + 1) & (YSLOTS - 1)), U);

    // ---- h-part MFMAs + in-register gates ----
    f32x4 aHN = {0.f,0.f,0.f,0.f};
    hpart(curR, curZ, aHN);
    #pragma unroll
    for (int i = 0; i < 4; ++i) {
      const float r = sigm(curR[i] + b_r);
      const float z = sigm(curZ[i] + b_z);
      const float n = fast_tanh(curXN[i] + b_xn + r * (aHN[i] + b_hn));
      h[i] = (1.0f - z) * n + z * h[i];
    }

    // ---- publish h(t+1) (+ y0(t) for L0); L1 writes y1 to dout ----
    if (layer == 0) {
      pubRounds(h, stateH((t + 1) & 1), (unsigned)(t + 2),
                stateY(t & (YSLOTS - 1)), (unsigned)(t + 1));
    } else {
      pubRounds(h, stateH((t + 1) & 1), (unsigned)(t + 2), nullptr, 0u);
      const int torig = dirr ? (T_LEN - 1 - t) : t;
      #pragma unroll
      for (int i = 0; i < 4; ++i) {
        const int brow = rowbase + q * 4 + i;
        dout[(size_t)brow * T_LEN * 2 * H_DIM + (size_t)torig * 2 * H_DIM + dirr * H_DIM + hcol] = h[i];
      }
    }
    if (t == T_LEN - 1) {
      #pragma unroll
      for (int i = 0; i < 4; ++i) {
        const int brow = rowbase + q * 4 + i;
        dout[(size_t)B_SZ * T_LEN * 2 * H_DIM +
             (size_t)(layer * B_SZ + brow) * 2 * H_DIM + dirr * H_DIM + hcol] = h[i];
      }
    }

    // ---- tails: next step's x-part ----
    if (layer == 0) {
      curR = nR; curZ = nZ; curXN = nXN;
    } else if (t + 1 < T_LEN) {
      gatherRetry(stateY((t + 1) & (YSLOTS - 1)), (unsigned)(t + 2), U);
      repackAll(U);                                 // tile := y0(t+1)
      curR[0]=curR[1]=curR[2]=curR[3]=0.f;
      curZ[0]=curZ[1]=curZ[2]=curZ[3]=0.f;
      curXN[0]=curXN[1]=curXN[2]=curXN[3]=0.f;
      xpart(curR, curZ, curXN);
    }
  }
}

extern "C" void kernel_launch(void* const* d_in, const int* in_sizes, int n_in,
                              void* d_out, int out_size, void* d_ws, size_t ws_size,
                              hipStream_t stream) {
  (void)in_sizes; (void)n_in; (void)out_size; (void)ws_size;
  const float* x    = (const float*)d_in[0];
  const float* enc  = (const float*)d_in[1];
  const float* WihF = (const float*)d_in[2];
  const float* WhhF = (const float*)d_in[3];
  const float* bihF = (const float*)d_in[4];
  const float* bhhF = (const float*)d_in[5];
  const float* WihB = (const float*)d_in[6];
  const float* WhhB = (const float*)d_in[7];
  const float* bihB = (const float*)d_in[8];
  const float* bhhB = (const float*)d_in[9];
  float* out = (float*)d_out;

  char* hT = (char*)d_ws;                 // 768KB tagged h exchange
  char* yT = (char*)d_ws + HT_BYTES;      // 3MB tagged y0 ring (16 slots)
  // zero ALL tags each replay (tags count from 1; memset-0 never matches)
  hipMemsetAsync(d_ws, 0, HT_BYTES + YT_BYTES, stream);

  dim3 grid(256), block(128);
  gru_wave2<<<grid, block, 0, stream>>>(x, enc, WihF, WhhF, bihF, bhhF,
                                        WihB, WhhB, bihB, bhhB, out, hT, yT);
}

// Round 11
// 5129.871 us; speedup vs baseline: 3.7650x; 2.6444x over previous
//
#include <hip/hip_runtime.h>
#include <hip/hip_bf16.h>
#include <cstdint>
#include <cstddef>

// Problem constants
#define T_LEN 1024
#define B_SZ  64
#define H_DIM 512
#define D_IN  512
#define YSLOTS 16

// Decomposition: 256 blocks x 256 threads, ONE block per CU.
//   layer = bid>>7 ; lbid = bid&127 ; grp = lbid&7 (dir*4+bg) ; cg = lbid>>3 (0..15)
// Block owns 16 batch rows (bg) x 32 h-cols [cg*32, cg*32+32) of ONE layer/dir.
// Sync community = 16 blocks (one (layer,dir,bg) group). L0 and L1 communities
// run concurrently on disjoint CUs; coupled via a 16-slot y0 ring + flags.
#define GROUP 16

typedef __attribute__((ext_vector_type(8))) short short8;
typedef __attribute__((ext_vector_type(4))) float f32x4;
typedef unsigned long long ull;

// LDS: Whh 6 subtiles (gate,colhalf) x 16 x 1024B = 96K | X 16K | H 16K | D 12K
#define OFF_WHH 0
#define OFF_X   98304
#define OFF_H   114688
#define OFF_D   131072
#define SMEM_BYTES 143360

__device__ __forceinline__ int swz(int row, int b) {
  return b ^ ((row & 7) << 4);   // 16B-granule XOR, breaks stride-1024 conflicts
}

__device__ __forceinline__ unsigned short f2bf(float f) {
  unsigned u = __float_as_uint(f);
  return (unsigned short)((u + 0x7FFFu + ((u >> 16) & 1u)) >> 16);   // RNE
}

__device__ __forceinline__ short8 pack8(float4 a, float4 b) {
  short8 v;
  v[0] = (short)f2bf(a.x); v[1] = (short)f2bf(a.y);
  v[2] = (short)f2bf(a.z); v[3] = (short)f2bf(a.w);
  v[4] = (short)f2bf(b.x); v[5] = (short)f2bf(b.y);
  v[6] = (short)f2bf(b.z); v[7] = (short)f2bf(b.w);
  return v;
}

__device__ __forceinline__ unsigned cvtpk(float lo, float hi) {
  unsigned r;
  asm("v_cvt_pk_bf16_f32 %0, %1, %2" : "=v"(r) : "v"(lo), "v"(hi));
  return r;
}
__device__ __forceinline__ short8 cvtpk8(float4 a, float4 b) {
  union { unsigned u[4]; short8 s; } cv;
  cv.u[0] = cvtpk(a.x, a.y); cv.u[1] = cvtpk(a.z, a.w);
  cv.u[2] = cvtpk(b.x, b.y); cv.u[3] = cvtpk(b.z, b.w);
  return cv.s;
}

__device__ __forceinline__ float sigm(float x) { return 1.0f / (1.0f + __expf(-x)); }
__device__ __forceinline__ float fast_tanh(float x) { return 1.0f - 2.0f / (__expf(2.0f * x) + 1.0f); }

__global__ __launch_bounds__(256, 1)
void gru_pipe(const float* __restrict__ x,
              const float* __restrict__ enc,
              const float* __restrict__ WihF, const float* __restrict__ WhhF,
              const float* __restrict__ bihF, const float* __restrict__ bhhF,
              const float* __restrict__ WihB, const float* __restrict__ WhhB,
              const float* __restrict__ bihB, const float* __restrict__ bhhB,
              float* __restrict__ dout,
              unsigned* __restrict__ flags,
              unsigned short* __restrict__ hbuf,
              unsigned short* __restrict__ yring)
{
  __shared__ alignas(16) char smem[SMEM_BYTES];

  const int bid   = blockIdx.x;
  const int layer = bid >> 7;
  const int lbid  = bid & 127;
  const int grp   = lbid & 7;        // dir*4+bg (mod-8: XCD affinity, perf only)
  const int dir   = grp >> 2;
  const int bg    = grp & 3;
  const int cg    = lbid >> 3;       // 0..15 (32-col groups)
  const int tid   = threadIdx.x;
  const int wv    = tid >> 6;        // wave 0..3
  const int tb    = tid >> 4;        // staging/batch row 0..15
  const int tc    = tid & 15;        // col-unit 0..15
  const int lane  = tid & 63;
  const int frow  = lane & 15;       // MFMA fragment row
  const int q     = lane >> 4;       // MFMA k-quarter
  const int hc0   = cg * 32;
  const int c0    = hc0 + tc;        // this thread's two gate-cols
  const int c1    = c0 + 16;
  const int brow  = bg * 16 + tb;
  const int dircol = dir * H_DIM;
  // wave job: main gate gw (0=r,1=z) on colhalf cw; n-gate quarter (colhalf cw, k-half kh)
  const int gw = wv & 1, cw = wv >> 1, kh = wv & 1;

  const float* Wih = (dir ? WihB : WihF) + (size_t)layer * 3 * H_DIM * D_IN;
  const float* Whh = (dir ? WhhB : WhhF) + (size_t)layer * 3 * H_DIM * H_DIM;
  const float* bih = (dir ? bihB : bihF) + (size_t)layer * 3 * H_DIM;
  const float* bhh = (dir ? bhhB : bhhF) + (size_t)layer * 3 * H_DIM;

  unsigned* fl  = flags + (layer * 8 + grp) * 64;  // own group's 16 producer flags
  unsigned* fl0 = flags + grp * 64;                // L0 counterpart
  unsigned* fl1 = flags + (8 + grp) * 64;          // L1 counterpart

  // ---- Stage Whh: 6 subtiles (gate g, colhalf ch), 16 rows x 1024B each ----
  #pragma unroll
  for (int g = 0; g < 3; ++g) {
    #pragma unroll
    for (int ch = 0; ch < 2; ++ch) {
      const float* s = Whh + (size_t)(g * H_DIM + hc0 + ch * 16 + tb) * H_DIM + tc * 32;
      char* r = smem + OFF_WHH + (g * 2 + ch) * 16384 + tb * 1024;
      #pragma unroll
      for (int u = 0; u < 4; ++u) {
        float4 a = ((const float4*)s)[u * 2];
        float4 b = ((const float4*)s)[u * 2 + 1];
        *(short8*)(r + swz(tb, tc * 64 + u * 16)) = pack8(a, b);
      }
    }
  }

  // ---- Wih B-fragments in registers: main job 16 chunks + n-quarter 8 chunks ----
  short8 wfM[16], wfN[8];
  {
    const float* pm = Wih + (size_t)(gw * H_DIM + hc0 + cw * 16 + frow) * D_IN;
    #pragma unroll
    for (int kc = 0; kc < 16; ++kc)
      wfM[kc] = cvtpk8(*(const float4*)(pm + kc * 32 + q * 8),
                       *(const float4*)(pm + kc * 32 + q * 8 + 4));
    const float* pn = Wih + (size_t)(2 * H_DIM + hc0 + cw * 16 + frow) * D_IN;
    #pragma unroll
    for (int j = 0; j < 8; ++j) {
      const int kc = kh * 8 + j;
      wfN[j] = cvtpk8(*(const float4*)(pn + kc * 32 + q * 8),
                      *(const float4*)(pn + kc * 32 + q * 8 + 4));
    }
  }

  // ---- biases (two cols per thread) and initial hidden state ----
  const float b_r0  = bih[c0] + bhh[c0];
  const float b_z0  = bih[H_DIM + c0] + bhh[H_DIM + c0];
  const float b_xn0 = bih[2 * H_DIM + c0];
  const float b_hn0 = bhh[2 * H_DIM + c0];
  const float b_r1  = bih[c1] + bhh[c1];
  const float b_z1  = bih[H_DIM + c1] + bhh[H_DIM + c1];
  const float b_xn1 = bih[2 * H_DIM + c1];
  const float b_hn1 = bhh[2 * H_DIM + c1];
  float h0 = enc[(size_t)layer * B_SZ * 2 * H_DIM + (size_t)brow * 2 * H_DIM + dircol + c0];
  float h1 = enc[(size_t)layer * B_SZ * 2 * H_DIM + (size_t)brow * 2 * H_DIM + dircol + c1];

  // ---- exchange bases (bf16, 512 cols x 16 rows per state) ----
  auto hbase = [&](int par) -> unsigned short* {
    return hbuf + (size_t)((((layer * 2 + par) * 2 + dir) * 4 + bg) * 16) * 512;
  };
  auto ybase = [&](int slot) -> unsigned short* {
    return yring + (size_t)(((slot * 2 + dir) * 4 + bg) * 16) * 512;
  };

  // ---- publish both colhalves (r3-proven shfl 7..4-pack, 8B agent stores) ----
  auto pub = [&](float v0, float v1, unsigned short* hrow, unsigned short* yrow) {
    unsigned a = f2bf(v0), b = f2bf(v1);
    unsigned a1 = __shfl_down(a, 1), a2 = __shfl_down(a, 2), a3 = __shfl_down(a, 3);
    unsigned b1 = __shfl_down(b, 1), b2 = __shfl_down(b, 2), b3 = __shfl_down(b, 3);
    if ((tc & 3) == 0) {
      ull pa = (ull)a | ((ull)a1 << 16) | ((ull)a2 << 32) | ((ull)a3 << 48);
      ull pb = (ull)b | ((ull)b1 << 16) | ((ull)b2 << 32) | ((ull)b3 << 48);
      __hip_atomic_store((ull*)(hrow + hc0 + tc),      pa, __ATOMIC_RELAXED, __HIP_MEMORY_SCOPE_AGENT);
      __hip_atomic_store((ull*)(hrow + hc0 + 16 + tc), pb, __ATOMIC_RELAXED, __HIP_MEMORY_SCOPE_AGENT);
      if (yrow) {
        __hip_atomic_store((ull*)(yrow + hc0 + tc),      pa, __ATOMIC_RELAXED, __HIP_MEMORY_SCOPE_AGENT);
        __hip_atomic_store((ull*)(yrow + hc0 + 16 + tc), pb, __ATOMIC_RELAXED, __HIP_MEMORY_SCOPE_AGENT);
      }
    }
  };

  auto spin16 = [&](unsigned* f, unsigned tgt) {
    if (tid < GROUP) {
      while (__hip_atomic_load(&f[tid], __ATOMIC_RELAXED, __HIP_MEMORY_SCOPE_AGENT) < tgt)
        __builtin_amdgcn_s_sleep(1);
    }
  };

  // gather a full 16x512 bf16 state into an LDS tile (r3-proven 8B agent loads)
  auto gatherRow = [&](const unsigned short* src, int ldsOff) {
    const ull* hb = (const ull*)(src + (size_t)tb * 512 + tc * 32);
    ull hv[8];
    #pragma unroll
    for (int u = 0; u < 8; ++u)
      hv[u] = __hip_atomic_load(hb + u, __ATOMIC_RELAXED, __HIP_MEMORY_SCOPE_AGENT);
    char* lh = smem + ldsOff + tb * 1024;
    #pragma unroll
    for (int u = 0; u < 4; ++u) {
      ull tmp[2] = {hv[2 * u], hv[2 * u + 1]};
      *(short8*)(lh + swz(tb, tc * 64 + u * 16)) = *(const short8*)tmp;
    }
  };

  auto stage_x = [&](int pos) {   // fp32 global row -> bf16 X tile (L0 only)
    const float* xrow = x + ((size_t)brow * T_LEN + pos) * D_IN;
    const float4* s4 = (const float4*)(xrow + tc * 32);
    char* lx = smem + OFF_X + tb * 1024;
    #pragma unroll
    for (int u = 0; u < 4; ++u) {
      float4 a = s4[u * 2];
      float4 b = s4[u * 2 + 1];
      *(short8*)(lx + swz(tb, tc * 64 + u * 16)) = pack8(a, b);
    }
  };

  // x-part: fused main gate (16 chunks) + xn quarter (8 chunks), B from registers
  auto xpart = [&](f32x4& aM, f32x4& aXN) {
    char* xr = smem + OFF_X + frow * 1024;
    #pragma unroll
    for (int kc = 0; kc < 16; ++kc) {
      short8 a = *(const short8*)(xr + swz(frow, kc * 64 + q * 16));
      aM = __builtin_amdgcn_mfma_f32_16x16x32_bf16(a, wfM[kc], aM, 0, 0, 0);
    }
    #pragma unroll
    for (int j = 0; j < 8; ++j) {
      const int kc = kh * 8 + j;
      short8 a = *(const short8*)(xr + swz(frow, kc * 64 + q * 16));
      aXN = __builtin_amdgcn_mfma_f32_16x16x32_bf16(a, wfN[j], aXN, 0, 0, 0);
    }
  };
  // h-part: fused main gate + hn quarter, B from Whh LDS subtiles
  auto hpart = [&](f32x4& aM, f32x4& aHN) {
    char* hr = smem + OFF_H + frow * 1024;
    char* wm = smem + OFF_WHH + (gw * 2 + cw) * 16384 + frow * 1024;
    char* wn = smem + OFF_WHH + (4 + cw) * 16384 + frow * 1024;
    #pragma unroll
    for (int kc = 0; kc < 16; ++kc) {
      const int o = swz(frow, kc * 64 + q * 16);
      short8 a = *(const short8*)(hr + o);
      short8 b = *(const short8*)(wm + o);
      aM = __builtin_amdgcn_mfma_f32_16x16x32_bf16(a, b, aM, 0, 0, 0);
    }
    #pragma unroll
    for (int j = 0; j < 8; ++j) {
      const int kc = kh * 8 + j;
      const int o = swz(frow, kc * 64 + q * 16);
      short8 a = *(const short8*)(hr + o);
      short8 b = *(const short8*)(wn + o);
      aHN = __builtin_amdgcn_mfma_f32_16x16x32_bf16(a, b, aHN, 0, 0, 0);
    }
  };
  // D tiles: fused main @ wv*1024 ; xn quarters @ 4096+wv*1024 ; hn @ 8192+wv*1024
  auto dwrite = [&](const f32x4& aM, const f32x4& aXN, const f32x4& aHN) {
    float* d0 = (float*)(smem + OFF_D + wv * 1024);
    float* d1 = (float*)(smem + OFF_D + 4096 + wv * 1024);
    float* d2 = (float*)(smem + OFF_D + 8192 + wv * 1024);
    #pragma unroll
    for (int r = 0; r < 4; ++r) {
      const int idx = (q * 4 + r) * 16 + ((frow + 4 * q) & 15);
      d0[idx] = aM[r]; d1[idx] = aXN[r]; d2[idx] = aHN[r];
    }
  };

  // ---- prologue: publish h(0) parity 0; flag=1; x-part for step 0 ----
  pub(h0, h1, hbase(0) + (size_t)tb * 512, nullptr);
  asm volatile("s_waitcnt vmcnt(0)" ::: "memory");
  __syncthreads();   // also covers Whh LDS staging
  if (tid == 0)
    __hip_atomic_store(&fl[cg], 1u, __ATOMIC_RELAXED, __HIP_MEMORY_SCOPE_AGENT);

  f32x4 aM = {0.f,0.f,0.f,0.f}, aXN = {0.f,0.f,0.f,0.f};
  if (layer == 0) {
    stage_x(dir ? (T_LEN - 1) : 0);
    __syncthreads();
    xpart(aM, aXN);
  } else {
    spin16(fl0, 2u);            // L0 published y0(pos_0) at flag 2
    __syncthreads();
    gatherRow(ybase(0), OFF_X);
    __syncthreads();
    xpart(aM, aXN);
  }

  for (int t = 0; t < T_LEN; ++t) {
    // ---- L0 backpressure (rare, amortized): before overwriting ring slots
    //      t..t+7 (overwriting y0(t-16)..y0(t-9)) require L1 flags >= t-7
    //      (flag f => consumed y0(f-2)). Steady lag ~3-7 => passes instantly.
    if (layer == 0 && t >= 16 && (t & 7) == 0)
      spin16(fl1, (unsigned)(t - 7));

    // ---- own-group barrier + h(t) gather ----
    spin16(fl, (unsigned)(t + 1));
    __syncthreads();
    gatherRow(hbase(t & 1), OFF_H);
    __syncthreads();

    // ---- h-part MFMAs (fused accs) + D write ----
    f32x4 aHN = {0.f,0.f,0.f,0.f};
    hpart(aM, aHN);
    dwrite(aM, aXN, aHN);
    __syncthreads();

    // ---- gates (two cols per thread) ----
    {
      const float* Df = (const float*)(smem + OFF_D);
      const int e = tb * 16 + ((tc + 4 * (tb >> 2)) & 15);
      const float r0 = sigm(Df[e] + b_r0);
      const float z0 = sigm(Df[256 + e] + b_z0);
      const float n0 = fast_tanh(Df[1024 + e] + Df[1280 + e] + b_xn0 +
                                 r0 * (Df[2048 + e] + Df[2304 + e] + b_hn0));
      h0 = (1.0f - z0) * n0 + z0 * h0;
      const float r1 = sigm(Df[512 + e] + b_r1);
      const float z1 = sigm(Df[768 + e] + b_z1);
      const float n1 = fast_tanh(Df[1536 + e] + Df[1792 + e] + b_xn1 +
                                 r1 * (Df[2560 + e] + Df[2816 + e] + b_hn1));
      h1 = (1.0f - z1) * n1 + z1 * h1;
    }

    // ---- publish h(t+1) (+ y0(t) ring for L0); L1 writes y1 out ----
    const int torig = dir ? (T_LEN - 1 - t) : t;
    pub(h0, h1, hbase((t + 1) & 1) + (size_t)tb * 512,
        (layer == 0) ? (ybase(t & (YSLOTS - 1)) + (size_t)tb * 512) : nullptr);
    if (layer == 1) {
      dout[(size_t)brow * T_LEN * 2 * H_DIM + (size_t)torig * 2 * H_DIM + dircol + c0] = h0;
      dout[(size_t)brow * T_LEN * 2 * H_DIM + (size_t)torig * 2 * H_DIM + dircol + c1] = h1;
    }
    if (t == T_LEN - 1) {
      dout[(size_t)B_SZ * T_LEN * 2 * H_DIM +
           (size_t)(layer * B_SZ + brow) * 2 * H_DIM + dircol + c0] = h0;
      dout[(size_t)B_SZ * T_LEN * 2 * H_DIM +
           (size_t)(layer * B_SZ + brow) * 2 * H_DIM + dircol + c1] = h1;
    }
    asm volatile("s_waitcnt vmcnt(0)" ::: "memory");
    __syncthreads();
    if (tid == 0)
      __hip_atomic_store(&fl[cg], (unsigned)(t + 2), __ATOMIC_RELAXED, __HIP_MEMORY_SCOPE_AGENT);

    // ---- tail: x-part for step t+1 ----
    if (t + 1 < T_LEN) {
      if (layer == 0) {
        stage_x(dir ? (T_LEN - 2 - t) : (t + 1));
        __syncthreads();
      } else {
        spin16(fl0, (unsigned)(t + 3));   // y0(t+1) ready (L0 flag t+3)
        __syncthreads();
        gatherRow(ybase((t + 1) & (YSLOTS - 1)), OFF_X);
        __syncthreads();
      }
      aM[0]=0.f;  aM[1]=0.f;  aM[2]=0.f;  aM[3]=0.f;
      aXN[0]=0.f; aXN[1]=0.f; aXN[2]=0.f; aXN[3]=0.f;
      xpart(aM, aXN);
    }
  }
}

extern "C" void kernel_launch(void* const* d_in, const int* in_sizes, int n_in,
                              void* d_out, int out_size, void* d_ws, size_t ws_size,
                              hipStream_t stream) {
  (void)in_sizes; (void)n_in; (void)out_size; (void)ws_size;
  const float* x    = (const float*)d_in[0];
  const float* enc  = (const float*)d_in[1];
  const float* WihF = (const float*)d_in[2];
  const float* WhhF = (const float*)d_in[3];
  const float* bihF = (const float*)d_in[4];
  const float* bhhF = (const float*)d_in[5];
  const float* WihB = (const float*)d_in[6];
  const float* WhhB = (const float*)d_in[7];
  const float* bihB = (const float*)d_in[8];
  const float* bhhB = (const float*)d_in[9];
  float* out = (float*)d_out;

  unsigned* flags = (unsigned*)d_ws;                                   // 4KB
  unsigned short* hbuf  = (unsigned short*)((char*)d_ws + 4096);       // 512KB
  unsigned short* yring = (unsigned short*)((char*)d_ws + 4096 + 524288); // 2MB
  hipMemsetAsync(d_ws, 0, 4096, stream);   // zero flags each replay (data is flag-gated)

  dim3 grid(256), block(256);
  gru_pipe<<<grid, block, 0, stream>>>(x, enc, WihF, WhhF, bihF, bhhF,
                                       WihB, WhhB, bihB, bhhB, out, flags, hbuf, yring);
}